// Round 2
// baseline (221.951 us; speedup 1.0000x reference)
//
#include <hip/hip_runtime.h>

#define GRID_N 112
#define O_MAX 48
#define HW_N (GRID_N * GRID_N)
#define NT 128
#define ROWS_MAX (O_MAX + 1)

typedef _Float16 half4_t __attribute__((ext_vector_type(4)));
typedef _Float16 half8_t __attribute__((ext_vector_type(8)));

// channel[b,h,w] = 0.5 + sum_{o<=n} sex[o,h]*sey[o,w]
//   sex[o<n] = -0.5*exp(-(h-xo)^2*INV), sex[n] = +0.5*exp(-(h-xL)^2*INV)
//   sey[o<n] =      exp(-(w-yo)^2*INV), sey[n] =      exp(-(w-yL)^2*INV)
// then zeroed where road_mask == 0.
__global__ __launch_bounds__(NT) void goalmap_kernel(
    const float* __restrict__ xL, const float* __restrict__ yL,
    const float* __restrict__ obj_list, const int* __restrict__ obj_num,
    const int* __restrict__ road_mask, float* __restrict__ out)
{
    constexpr float INV = 1.0f / (2.0f * 5.0f * 5.0f);  // SIGMA = 5.0

    __shared__ _Float16 sex[ROWS_MAX * GRID_N];  // [o][h], sign+0.5 folded
    __shared__ _Float16 sey[ROWS_MAX * GRID_N];  // [o][w]

    const int b   = blockIdx.x;
    const int tid = threadIdx.x;
    const int n   = obj_num[b];          // uniform per block, in [0, 48]
    const int rows = n + 1;              // objects + goal row
    const float xl = xL[b];
    const float yl = yL[b];

    // --- Stage 1: build signed 1-D gaussian tables (f16) in LDS ---
    for (int i = tid; i < rows * GRID_N; i += NT) {
        int o = i / GRID_N;
        int p = i - o * GRID_N;
        float cx, cy, sgn;
        if (o < n) {
            cx  = obj_list[(b * O_MAX + o) * 2 + 1];  // index 1 -> H dim
            cy  = obj_list[(b * O_MAX + o) * 2 + 0];  // index 0 -> W dim
            sgn = -0.5f;
        } else {
            cx  = xl;
            cy  = yl;
            sgn = 0.5f;
        }
        float dx = (float)p - cx;
        float dy = (float)p - cy;
        sex[i] = (_Float16)(sgn * __expf(-dx * dx * INV));
        sey[i] = (_Float16)(__expf(-dy * dy * INV));
    }
    __syncthreads();

    const int* rm = road_mask + (size_t)b * HW_N;
    float*     op = out       + (size_t)b * HW_N;

    // --- Stage 2: each thread owns a 4(h) x 8(w) register tile ---
    const int NTILES = (GRID_N / 4) * (GRID_N / 8);  // 28 * 14 = 392
    for (int t = tid; t < NTILES; t += NT) {
        int hp = t / 14;
        int wq = t - hp * 14;
        int h = hp * 4;
        int w = wq * 8;

        float acc[4][8];
        #pragma unroll
        for (int r = 0; r < 4; ++r)
            #pragma unroll
            for (int c = 0; c < 8; ++c) acc[r][c] = 0.f;

        #pragma unroll 2
        for (int o = 0; o < rows; ++o) {
            half4_t ex4 = *(const half4_t*)&sex[o * GRID_N + h];  // ds_read_b64
            half8_t ey8 = *(const half8_t*)&sey[o * GRID_N + w];  // ds_read_b128
            float ef[4], gf[8];
            #pragma unroll
            for (int r = 0; r < 4; ++r) ef[r] = (float)ex4[r];
            #pragma unroll
            for (int c = 0; c < 8; ++c) gf[c] = (float)ey8[c];
            #pragma unroll
            for (int r = 0; r < 4; ++r)
                #pragma unroll
                for (int c = 0; c < 8; ++c)
                    acc[r][c] = fmaf(ef[r], gf[c], acc[r][c]);
        }

        #pragma unroll
        for (int r = 0; r < 4; ++r) {
            int base = (h + r) * GRID_N + w;
            int4 m0 = *(const int4*)&rm[base];
            int4 m1 = *(const int4*)&rm[base + 4];
            float4 v0, v1;
            v0.x = 0.5f + acc[r][0];
            v0.y = 0.5f + acc[r][1];
            v0.z = 0.5f + acc[r][2];
            v0.w = 0.5f + acc[r][3];
            v1.x = 0.5f + acc[r][4];
            v1.y = 0.5f + acc[r][5];
            v1.z = 0.5f + acc[r][6];
            v1.w = 0.5f + acc[r][7];
            v0.x = (m0.x == 0) ? 0.f : v0.x;
            v0.y = (m0.y == 0) ? 0.f : v0.y;
            v0.z = (m0.z == 0) ? 0.f : v0.z;
            v0.w = (m0.w == 0) ? 0.f : v0.w;
            v1.x = (m1.x == 0) ? 0.f : v1.x;
            v1.y = (m1.y == 0) ? 0.f : v1.y;
            v1.z = (m1.z == 0) ? 0.f : v1.z;
            v1.w = (m1.w == 0) ? 0.f : v1.w;
            *(float4*)&op[base]     = v0;
            *(float4*)&op[base + 4] = v1;
        }
    }
}

extern "C" void kernel_launch(void* const* d_in, const int* in_sizes, int n_in,
                              void* d_out, int out_size, void* d_ws, size_t ws_size,
                              hipStream_t stream) {
    const float* xL        = (const float*)d_in[0];
    const float* yL        = (const float*)d_in[1];
    const float* obj_list  = (const float*)d_in[2];
    const int*   obj_num   = (const int*)d_in[3];
    const int*   road_mask = (const int*)d_in[4];
    float*       out       = (float*)d_out;
    const int B = in_sizes[0];  // 2048

    goalmap_kernel<<<B, NT, 0, stream>>>(xL, yL, obj_list, obj_num, road_mask, out);
}

// Round 3
// 219.616 us; speedup vs baseline: 1.0106x; 1.0106x over previous
//
#include <hip/hip_runtime.h>

#define GRID_N 112
#define O_MAX 48
#define HW_N (GRID_N * GRID_N)
#define NT 256
#define KPAD 64          // K padded to 64 (2 MFMA K-steps of 32)
#define LSTR 72          // LDS row stride in f16 (144 B -> 2-way bank alias = free)

typedef _Float16 half8  __attribute__((ext_vector_type(8)));
typedef _Float16 half2v __attribute__((ext_vector_type(2)));
typedef float    f32x4  __attribute__((ext_vector_type(4)));

// channel[b,h,w] = 0.5 + sum_k A[h,k]*B[w,k]; A rows carry sign/scale:
//   k<n: A[h,k] = -0.5*exp(-(h-xo_k)^2*INV), B[w,k] = exp(-(w-yo_k)^2*INV)
//   k=n: A[h,k] = +0.5*exp(-(h-xL)^2*INV),  B[w,k] = exp(-(w-yL)^2*INV)
//   k>n: 0
// zeroed where road_mask == 0.
__global__ __launch_bounds__(NT) void goalmap_kernel(
    const float* __restrict__ xL, const float* __restrict__ yL,
    const float* __restrict__ obj_list, const int* __restrict__ obj_num,
    const int* __restrict__ road_mask, float* __restrict__ out)
{
    constexpr float INV = 1.0f / (2.0f * 5.0f * 5.0f);  // SIGMA = 5.0

    __shared__ _Float16 exT[GRID_N * LSTR];  // [h][k]
    __shared__ _Float16 eyT[GRID_N * LSTR];  // [w][k]

    const int b   = blockIdx.x;
    const int tid = threadIdx.x;
    const int n   = obj_num[b];              // in [0, 48]
    const float xl = xL[b];
    const float yl = yL[b];
    const float* ob = obj_list + (size_t)b * O_MAX * 2;

    // --- Stage 1: build transposed f16 tables, K zero-padded to 64 ---
    // 112 positions x 32 k-pairs per table
    for (int i = tid; i < GRID_N * (KPAD / 2); i += NT) {
        int pos = i >> 5;
        int o0  = (i & 31) * 2;
        half2v vx, vy;
        #pragma unroll
        for (int j = 0; j < 2; ++j) {
            int o = o0 + j;
            float valx = 0.f, valy = 0.f;
            if (o <= n) {
                float cx, cy, s;
                if (o < n) { cx = ob[o * 2 + 1]; cy = ob[o * 2 + 0]; s = -0.5f; }
                else       { cx = xl;            cy = yl;            s =  0.5f; }
                float dx = (float)pos - cx;
                float dy = (float)pos - cy;
                valx = s * __expf(-dx * dx * INV);
                valy =     __expf(-dy * dy * INV);
            }
            vx[j] = (_Float16)valx;
            vy[j] = (_Float16)valy;
        }
        *(half2v*)&exT[pos * LSTR + o0] = vx;
        *(half2v*)&eyT[pos * LSTR + o0] = vy;
    }
    __syncthreads();

    const int* rm = road_mask + (size_t)b * HW_N;
    float*     op = out       + (size_t)b * HW_N;

    const int lane = tid & 63;
    const int wid  = tid >> 6;      // 4 waves
    const int m    = lane & 15;
    const int quad = lane >> 4;

    // --- Stage 2: 7x7 = 49 tiles of 16x16, round-robin over 4 waves ---
    for (int t = wid; t < 49; t += 4) {
        int th = t / 7;
        int tw = t - th * 7;

        const _Float16* arow = &exT[(th * 16 + m) * LSTR + quad * 8];
        const _Float16* brow = &eyT[(tw * 16 + m) * LSTR + quad * 8];
        half8 a0 = *(const half8*)arow;            // k 0..31 slice
        half8 b0 = *(const half8*)brow;
        half8 a1 = *(const half8*)(arow + 32);     // k 32..63 slice
        half8 b1 = *(const half8*)(brow + 32);

        f32x4 acc = {0.f, 0.f, 0.f, 0.f};
        acc = __builtin_amdgcn_mfma_f32_16x16x32_f16(a0, b0, acc, 0, 0, 0);
        acc = __builtin_amdgcn_mfma_f32_16x16x32_f16(a1, b1, acc, 0, 0, 0);

        // C/D layout: col = lane&15 (n -> w), row = quad*4 + reg (m -> h)
        int h0 = th * 16 + quad * 4;
        int w0 = tw * 16 + m;
        #pragma unroll
        for (int r = 0; r < 4; ++r) {
            int idx = (h0 + r) * GRID_N + w0;
            int mv = rm[idx];
            float v = 0.5f + acc[r];
            op[idx] = (mv == 0) ? 0.f : v;
        }
    }
}

extern "C" void kernel_launch(void* const* d_in, const int* in_sizes, int n_in,
                              void* d_out, int out_size, void* d_ws, size_t ws_size,
                              hipStream_t stream) {
    const float* xL        = (const float*)d_in[0];
    const float* yL        = (const float*)d_in[1];
    const float* obj_list  = (const float*)d_in[2];
    const int*   obj_num   = (const int*)d_in[3];
    const int*   road_mask = (const int*)d_in[4];
    float*       out       = (float*)d_out;
    const int B = in_sizes[0];  // 2048

    goalmap_kernel<<<B, NT, 0, stream>>>(xL, yL, obj_list, obj_num, road_mask, out);
}